// Round 9
// baseline (262.067 us; speedup 1.0000x reference)
//
#include <hip/hip_runtime.h>
#include <hip/hip_bf16.h>
#include <math.h>

#define N 20000
#define E 160000
#define MUL 64
#define EDIM 8
#define NZ 4
#define NB 256            // blocks in the barrier-synced CSR kernel

#define INV_SQRT_MUL 0.125f
#define INV_E 0.35355339059327373f
#define INV_N 0.35355339059327373f
#define INV2 0.08838834764831845f
#define INV_SC 0.0625f
#define INV_SQRT3 0.5773502691896258f

typedef unsigned short u16;
typedef unsigned int u32;
typedef short bf16x8 __attribute__((ext_vector_type(8)));
typedef float f32x4 __attribute__((ext_vector_type(4)));

__device__ __forceinline__ float silu(float v) {
    return v / (1.0f + __expf(-v));
}
__device__ __forceinline__ u16 f2bf(float f) {
    union { float f; unsigned int u; } v; v.f = f;
    unsigned int r = (v.u + 0x7FFFu + ((v.u >> 16) & 1u)) >> 16;
    return (u16)r;
}
__device__ __forceinline__ float bflo(u32 p) {
    union { unsigned int u; float f; } v; v.u = p << 16; return v.f;
}
__device__ __forceinline__ float bfhi(u32 p) {
    union { unsigned int u; float f; } v; v.u = p & 0xFFFF0000u; return v.f;
}
#define MFMA(a, b, c) __builtin_amdgcn_mfma_f32_16x16x32_bf16(a, b, c, 0, 0, 0)

// Layouts:
//  A1 [N][192]:  0..127 gathered s0 (scales folded), 128..191 bf16(x0)
//  A2 [3N][384]: 0..127 gathered s1, 128..383 bf16(x1[:,d]*attr[z]*INV_SC), col=128+u*4+z
//  x1p [3N][64] bf16(x1) for the h-GEMM
//  Bt1m [128][128] = W20^T; Bt1z [4][128][64] = Wsc0_z^T * INV_SC
//  Bt2  [64][384]: k<128 W21^T, k>=128 Wsc1 flat (u*4+z)
//  W0b/W1b [64][64] = lin1^T * INV_SQRT_MUL

// ---------------------------------------------------------------------------
// Front: grid-partitioned [prep | wconv | hid | hist]
// ---------------------------------------------------------------------------
#define PREP_B  5000
#define WCONV_B 320
#define HID_B   5000
#define HIST_B  625

__global__ __launch_bounds__(256) void k_front(
    const float* __restrict__ x, const float* __restrict__ attrs,
    const float* __restrict__ eemb, const int* __restrict__ eidx,
    const float* __restrict__ W20, const float* __restrict__ Wsc0,
    const float* __restrict__ W21, const float* __restrict__ Wsc1,
    const float* __restrict__ W0, const float* __restrict__ W1,
    const float* __restrict__ Wm1,
    u16* __restrict__ A1, u16* __restrict__ A2, u16* __restrict__ x1p,
    u16* __restrict__ Bt1m, u16* __restrict__ Bt1z, u16* __restrict__ Bt2,
    u16* __restrict__ W0b, u16* __restrict__ W1b,
    float* __restrict__ hid, int* __restrict__ counts)
{
    const int b = blockIdx.x;
    const int tid = threadIdx.x;
    __shared__ float xr[4][256];

    if (b < PREP_B) {
        const int n0 = b * 4;
        #pragma unroll
        for (int t = 0; t < 4; ++t)
            xr[t][tid] = x[(size_t)(n0 + t) * 256 + tid];
        __syncthreads();
        #pragma unroll
        for (int t = 0; t < 4; ++t) {
            const int n = n0 + t;
            const float at = attrs[(size_t)n * 4 + (tid & 3)] * INV_SC;
            const int u = tid >> 2;
            #pragma unroll
            for (int d = 0; d < 3; ++d)
                A2[((size_t)n * 3 + d) * 384 + 128 + tid] = f2bf(xr[t][64 + u * 3 + d] * at);
            if (tid < 64) {
                A1[(size_t)n * 192 + 128 + tid] = f2bf(xr[t][tid]);
            } else {
                int q = tid - 64;
                int d = q >> 6, uu = q & 63;
                x1p[((size_t)n * 3 + d) * 64 + uu] = f2bf(xr[t][64 + uu * 3 + d]);
            }
        }
    } else if (b < PREP_B + WCONV_B) {
        int i = (b - PREP_B) * 256 + tid;
        if (i < 16384) {                               // Bt1m[w][k]
            int w = i >> 7, k = i & 127;
            Bt1m[i] = f2bf(W20[k * 128 + w]);
        } else if (i < 49152) {                        // Bt1z[z][w][k]
            int j = i - 16384;
            int z = j >> 13, r = j & 8191, w = r >> 6, k = r & 63;
            Bt1z[j] = f2bf(Wsc0[(k * 4 + z) * 128 + w] * INV_SC);
        } else if (i < 73728) {                        // Bt2[w][k] full 384
            int j = i - 49152;
            int w = j / 384, k = j % 384;
            float v = (k < 128) ? W21[k * 64 + w] : Wsc1[(k - 128) * 64 + w];
            Bt2[j] = f2bf(v);
        } else if (i < 77824) {
            int j = i - 73728;
            int v = j >> 6, u = j & 63;
            W0b[j] = f2bf(W0[u * 64 + v] * INV_SQRT_MUL);
        } else {
            int j = i - 77824;
            int v = j >> 6, u = j & 63;
            W1b[j] = f2bf(W1[u * 64 + v] * INV_SQRT_MUL);
        }
    } else if (b < PREP_B + WCONV_B + HID_B) {
        int i = (b - PREP_B - WCONV_B) * 256 + tid;
        int e = i >> 3, k = i & 7;
        float s = 0.f;
        #pragma unroll
        for (int j = 0; j < 8; ++j)
            s += eemb[(size_t)e * 8 + j] * Wm1[j * 8 + k];
        hid[i] = silu(s * INV_E);
    } else {
        int e = (b - PREP_B - WCONV_B - HID_B) * 256 + tid;
        if (e < E) atomicAdd(&counts[eidx[E + e]], 1);
    }
}

// ---------------------------------------------------------------------------
// Barrier-synced CSR kernel (256 blocks, all co-resident):
//   P1 per-block chunk scan of counts -> blockSum
//   P2 cross-block prefix -> offsets + cursor (atomic stores)
//   P3 scatter -> perm_e/perm_src;  P4 h-GEMM -> hc
// ---------------------------------------------------------------------------
__device__ __forceinline__ void gbar(int* bar, int idx) {
    __syncthreads();
    if (threadIdx.x == 0) {
        __hip_atomic_fetch_add(&bar[idx], 1, __ATOMIC_ACQ_REL, __HIP_MEMORY_SCOPE_AGENT);
        while (__hip_atomic_load(&bar[idx], __ATOMIC_ACQUIRE, __HIP_MEMORY_SCOPE_AGENT) < NB) {}
    }
    __syncthreads();
}

#define CHUNK 80   // 256 * 80 = 20480 >= N

__global__ __launch_bounds__(256) void k_csr(
    const int* __restrict__ counts, int* __restrict__ blockSum,
    int* __restrict__ bar, int* __restrict__ offsets, int* __restrict__ cursor,
    const int* __restrict__ eidx, int* __restrict__ perm_e, int* __restrict__ perm_src,
    const u16* __restrict__ A1, const u16* __restrict__ x1p,
    const u16* __restrict__ W0b, const u16* __restrict__ W1b,
    u16* __restrict__ hc)
{
    const int b = blockIdx.x;
    const int tid = threadIdx.x;
    const int start = b * CHUNK;
    __shared__ int lc[256];
    __shared__ int ls[256];

    // P1: intra-chunk inclusive scan
    int v = 0;
    if (tid < CHUNK && start + tid < N) v = counts[start + tid];
    lc[tid] = v;
    __syncthreads();
    for (int off = 1; off < 256; off <<= 1) {
        int t = (tid >= off) ? lc[tid - off] : 0;
        __syncthreads();
        lc[tid] += t;
        __syncthreads();
    }
    if (tid == 0)
        __hip_atomic_store(&blockSum[b], lc[255], __ATOMIC_RELEASE, __HIP_MEMORY_SCOPE_AGENT);
    gbar(bar, 0);

    // P2: cross-block prefix, write offsets + cursor
    int bs = __hip_atomic_load(&blockSum[tid], __ATOMIC_ACQUIRE, __HIP_MEMORY_SCOPE_AGENT);
    ls[tid] = bs;
    __syncthreads();
    for (int off = 1; off < 256; off <<= 1) {
        int t = (tid >= off) ? ls[tid - off] : 0;
        __syncthreads();
        ls[tid] += t;
        __syncthreads();
    }
    const int blockOff = ls[b] - lc[255];       // exclusive prefix of this block
    if (tid < CHUNK && start + tid < N) {
        int o = blockOff + lc[tid] - v;         // exclusive within chunk
        __hip_atomic_store(&offsets[start + tid], o, __ATOMIC_RELEASE, __HIP_MEMORY_SCOPE_AGENT);
        __hip_atomic_store(&cursor[start + tid], o, __ATOMIC_RELEASE, __HIP_MEMORY_SCOPE_AGENT);
    }
    if (b == 0 && tid == 0)
        __hip_atomic_store(&offsets[N], ls[255], __ATOMIC_RELEASE, __HIP_MEMORY_SCOPE_AGENT);
    gbar(bar, 1);

    // P3: scatter
    for (int e = b * 256 + tid; e < E; e += NB * 256) {
        int src = eidx[e];
        int pos = atomicAdd(&cursor[eidx[E + e]], 1);
        perm_e[pos] = e;
        perm_src[pos] = src;
    }

    // P4: h-GEMM (independent of P1-P3 data; inputs from k_front)
    const int lane = tid & 63;
    const int wave = tid >> 6;
    const int quad = lane >> 4, l16 = lane & 15;
    for (int g = b * 4 + wave; g < 5000; g += NB * 4) {
        const bool isC1 = (g >= 1250);
        const int row0 = isC1 ? (g - 1250) * 16 : g * 16;
        const u16* Ap = isC1 ? (x1p + (size_t)(row0 + l16) * 64)
                             : (A1 + (size_t)(row0 + l16) * 192 + 128);
        const u16* Bp = isC1 ? W1b : W0b;
        f32x4 acc[4] = {};
        #pragma unroll
        for (int k0 = 0; k0 < 64; k0 += 32) {
            bf16x8 a = *(const bf16x8*)(Ap + k0 + quad * 8);
            #pragma unroll
            for (int ct = 0; ct < 4; ++ct) {
                bf16x8 bb = *(const bf16x8*)(Bp + (size_t)(ct * 16 + l16) * 64 + k0 + quad * 8);
                acc[ct] = MFMA(a, bb, acc[ct]);
            }
        }
        #pragma unroll
        for (int ct = 0; ct < 4; ++ct) {
            #pragma unroll
            for (int r = 0; r < 4; ++r) {
                int row = row0 + quad * 4 + r;
                int vv = ct * 16 + l16;
                if (!isC1) {
                    hc[(size_t)row * 256 + vv * 4] = f2bf(acc[ct][r]);
                } else {
                    int n = row / 3, d = row - 3 * (row / 3);
                    hc[(size_t)n * 256 + vv * 4 + 1 + d] = f2bf(acc[ct][r]);
                }
            }
        }
    }
}

// ---------------------------------------------------------------------------
// Gather v5: 2 waves per node (even/odd edges), depth-1 prefetch, LDS combine.
// ---------------------------------------------------------------------------
__global__ __launch_bounds__(256) void k_gather(
    const int* __restrict__ perm_e, const int* __restrict__ perm_src,
    const int* __restrict__ offsets,
    const float* __restrict__ eattr, const float* __restrict__ hid,
    const u32* __restrict__ hc2, const float* __restrict__ Wm2,
    u16* __restrict__ A1, u16* __restrict__ A2)
{
    const int lane = threadIdx.x & 63;
    const int wave = threadIdx.x >> 6;
    const int pair = wave >> 1;
    const int half = wave & 1;
    const int n = blockIdx.x * 2 + pair;
    const int beg = offsets[n];
    const int deg = offsets[n + 1] - beg;
    const int cw = (deg > half) ? ((deg - half + 1) >> 1) : 0;
    const int p0 = beg + half;

    float wm0[8], wm1[8], wm2r[8], wm3[8];
    #pragma unroll
    for (int k = 0; k < 8; ++k) {
        wm0[k]  = Wm2[k * 256 + lane];
        wm1[k]  = Wm2[k * 256 + 64 + lane];
        wm2r[k] = Wm2[k * 256 + 128 + lane];
        wm3[k]  = Wm2[k * 256 + 192 + lane];
    }

    float acc0a = 0.f, acc0b = 0.f;
    float s1a[3] = {0.f, 0.f, 0.f}, s1b[3] = {0.f, 0.f, 0.f};

    for (int bb = 0; bb < cw; bb += 64) {
        const int cnt = min(64, cw - bb);
        int e_l = 0, s_l = 0;
        if (lane < cnt) {
            int pos = p0 + 2 * (bb + lane);
            e_l = perm_e[pos];
            s_l = perm_src[pos];
        }
        int eC = __shfl(e_l, 0, 64), sC = __shfl(s_l, 0, 64);
        float4 eaC = ((const float4*)eattr)[eC];
        float4 hAC = ((const float4*)hid)[(size_t)eC * 2];
        float4 hBC = ((const float4*)hid)[(size_t)eC * 2 + 1];
        uint2  hpC = ((const uint2*)hc2)[(size_t)sC * 64 + lane];
        for (int i = 0; i < cnt; ++i) {
            const int ii = (i + 1 < cnt) ? i + 1 : i;
            const int eN = __shfl(e_l, ii, 64), sN = __shfl(s_l, ii, 64);
            const float4 eaN = ((const float4*)eattr)[eN];
            const float4 hAN = ((const float4*)hid)[(size_t)eN * 2];
            const float4 hBN = ((const float4*)hid)[(size_t)eN * 2 + 1];
            const uint2  hpN = ((const uint2*)hc2)[(size_t)sN * 64 + lane];

            float w1 = hAC.x*wm0[0]+hAC.y*wm0[1]+hAC.z*wm0[2]+hAC.w*wm0[3]
                     + hBC.x*wm0[4]+hBC.y*wm0[5]+hBC.z*wm0[6]+hBC.w*wm0[7];
            float w2 = hAC.x*wm1[0]+hAC.y*wm1[1]+hAC.z*wm1[2]+hAC.w*wm1[3]
                     + hBC.x*wm1[4]+hBC.y*wm1[5]+hBC.z*wm1[6]+hBC.w*wm1[7];
            float w3 = hAC.x*wm2r[0]+hAC.y*wm2r[1]+hAC.z*wm2r[2]+hAC.w*wm2r[3]
                     + hBC.x*wm2r[4]+hBC.y*wm2r[5]+hBC.z*wm2r[6]+hBC.w*wm2r[7];
            float w4 = hAC.x*wm3[0]+hAC.y*wm3[1]+hAC.z*wm3[2]+hAC.w*wm3[3]
                     + hBC.x*wm3[4]+hBC.y*wm3[5]+hBC.z*wm3[6]+hBC.w*wm3[7];
            const float g0 = bflo(hpC.x), g1x = bfhi(hpC.x);
            const float g1y = bflo(hpC.y), g1z = bfhi(hpC.y);
            acc0a += w1 * g0 * eaC.x;
            acc0b += w4 * (g1x * eaC.y + g1y * eaC.z + g1z * eaC.w);
            const float wg = w2 * g0, w3a = w3 * eaC.x;
            s1a[0] += wg * eaC.y;  s1a[1] += wg * eaC.z;  s1a[2] += wg * eaC.w;
            s1b[0] += w3a * g1x;   s1b[1] += w3a * g1y;   s1b[2] += w3a * g1z;

            eaC = eaN; hAC = hAN; hBC = hBN; hpC = hpN;
        }
    }

    __shared__ float comb[2][64][9];
    if (half == 1) {
        comb[pair][lane][0] = acc0a;  comb[pair][lane][1] = acc0b;
        comb[pair][lane][2] = s1a[0]; comb[pair][lane][3] = s1a[1];
        comb[pair][lane][4] = s1a[2]; comb[pair][lane][5] = s1b[0];
        comb[pair][lane][6] = s1b[1]; comb[pair][lane][7] = s1b[2];
    }
    __syncthreads();
    if (half == 0) {
        acc0a  += comb[pair][lane][0];  acc0b  += comb[pair][lane][1];
        s1a[0] += comb[pair][lane][2];  s1a[1] += comb[pair][lane][3];
        s1a[2] += comb[pair][lane][4];  s1b[0] += comb[pair][lane][5];
        s1b[1] += comb[pair][lane][6];  s1b[2] += comb[pair][lane][7];

        const float f = INV_E * INV_N * INV2;
        u16* a1p = &A1[(size_t)n * 192];
        a1p[lane]      = f2bf(acc0a * f);
        a1p[64 + lane] = f2bf(acc0b * f * INV_SQRT3);
        #pragma unroll
        for (int d = 0; d < 3; ++d) {
            u16* a2p = &A2[((size_t)n * 3 + d) * 384];
            a2p[lane]      = f2bf(s1a[d] * f);
            a2p[64 + lane] = f2bf(s1b[d] * f);
        }
    }
}

// ---------------------------------------------------------------------------
// Fused post-GEMM + epilogue v5: 16 nodes/block; t1 single-acc (384-col A2),
// t0 = main + 4 z-sliced accs (192-col A1). 13 f32x4 accumulators total.
// ---------------------------------------------------------------------------
__global__ __launch_bounds__(256) void k_gemm_fused(
    const u16* __restrict__ A1, const u16* __restrict__ A2,
    const u16* __restrict__ Bt1m, const u16* __restrict__ Bt1z,
    const u16* __restrict__ Bt2,
    const float* __restrict__ attrs, const float* __restrict__ x,
    float* __restrict__ out)
{
    const int lane = threadIdx.x & 63;
    const int wave = threadIdx.x >> 6;
    const int quad = lane >> 4, l16 = lane & 15;
    const int n0 = blockIdx.x * 16;

    __shared__ float st0[16][132];
    __shared__ float st1[48][68];
    __shared__ float sat[16][4];
    if (threadIdx.x < 64)
        sat[threadIdx.x >> 2][threadIdx.x & 3] =
            attrs[(size_t)(n0 + (threadIdx.x >> 2)) * 4 + (threadIdx.x & 3)];

    const u16* a0p  = A1 + (size_t)(n0 + l16) * 192 + quad * 8;
    const u16* a1p  = A2 + (size_t)(3 * n0 + l16) * 384 + quad * 8;
    const u16* b0p  = Bt1m + (size_t)(wave * 16 + l16) * 128 + quad * 8;
    const u16* b1p  = Bt1m + (size_t)((wave + 4) * 16 + l16) * 128 + quad * 8;
    const u16* bz0p = Bt1z + (size_t)(wave * 16 + l16) * 64 + quad * 8;
    const u16* bz1p = Bt1z + (size_t)((wave + 4) * 16 + l16) * 64 + quad * 8;
    const u16* b2p  = Bt2 + (size_t)(wave * 16 + l16) * 384 + quad * 8;

    f32x4 m0 = {}, m1 = {}, m2 = {}, m3 = {}, m4 = {};
    f32x4 z0[4] = {}, z1[4] = {};

    #pragma unroll
    for (int kt = 0; kt < 12; ++kt) {          // t1: full 384
        const int ko = kt * 32;
        bf16x8 a1 = *(const bf16x8*)(a1p + ko);
        bf16x8 a2 = *(const bf16x8*)(a1p + 16 * 384 + ko);
        bf16x8 a3 = *(const bf16x8*)(a1p + 32 * 384 + ko);
        bf16x8 b2 = *(const bf16x8*)(b2p + ko);
        m2 = MFMA(a1, b2, m2);
        m3 = MFMA(a2, b2, m3);
        m4 = MFMA(a3, b2, m4);
    }
    #pragma unroll
    for (int kt = 0; kt < 4; ++kt) {           // t0 main: gathered 128
        const int ko = kt * 32;
        bf16x8 a0 = *(const bf16x8*)(a0p + ko);
        bf16x8 b0 = *(const bf16x8*)(b0p + ko);
        bf16x8 b1 = *(const bf16x8*)(b1p + ko);
        m0 = MFMA(a0, b0, m0);
        m1 = MFMA(a0, b1, m1);
    }
    #pragma unroll
    for (int kt = 0; kt < 2; ++kt) {           // t0 sc: x0 @ Wsc_z
        const int ko = kt * 32;
        bf16x8 a0 = *(const bf16x8*)(a0p + 128 + ko);
        #pragma unroll
        for (int z = 0; z < 4; ++z) {
            bf16x8 c0 = *(const bf16x8*)(bz0p + z * 8192 + ko);
            bf16x8 c1 = *(const bf16x8*)(bz1p + z * 8192 + ko);
            z0[z] = MFMA(a0, c0, z0[z]);
            z1[z] = MFMA(a0, c1, z1[z]);
        }
    }
    __syncthreads();

    #pragma unroll
    for (int r = 0; r < 4; ++r) {
        const int r0 = quad * 4 + r;
        const float ta = sat[r0][0], tb = sat[r0][1],
                    tc = sat[r0][2], td = sat[r0][3];
        st0[r0][wave * 16 + l16] =
            m0[r] + ta * z0[0][r] + tb * z0[1][r] + tc * z0[2][r] + td * z0[3][r];
        st0[r0][(wave + 4) * 16 + l16] =
            m1[r] + ta * z1[0][r] + tb * z1[1][r] + tc * z1[2][r] + td * z1[3][r];
        st1[r0][wave * 16 + l16]      = m2[r];
        st1[16 + r0][wave * 16 + l16] = m3[r];
        st1[32 + r0][wave * 16 + l16] = m4[r];
    }
    __syncthreads();

    const int c = threadIdx.x;
    #pragma unroll
    for (int t = 0; t < 16; ++t) {
        const float xv = x[(size_t)(n0 + t) * 256 + c];
        float o;
        if (c < 64) {
            o = xv + silu(st0[t][c]);
        } else {
            int r = c - 64;
            int w = (r * 21846) >> 16;      // r/3
            int d = r - w * 3;
            o = xv + silu(st0[t][64 + w]) * st1[t * 3 + d][w];
        }
        out[(size_t)(n0 + t) * 256 + c] = o;
    }
}

extern "C" void kernel_launch(void* const* d_in, const int* in_sizes, int n_in,
                              void* d_out, int out_size, void* d_ws, size_t ws_size,
                              hipStream_t stream) {
    const float* node_feats = (const float*)d_in[0];
    const float* node_attrs = (const float*)d_in[1];
    const float* edge_attrs = (const float*)d_in[2];
    const float* edge_emb   = (const float*)d_in[3];
    const float* W_lin1_0   = (const float*)d_in[4];
    const float* W_lin1_1   = (const float*)d_in[5];
    const float* W_mlp1     = (const float*)d_in[6];
    const float* W_mlp2     = (const float*)d_in[7];
    const float* W_lin2_0   = (const float*)d_in[8];
    const float* W_lin2_1   = (const float*)d_in[9];
    const float* W_sc0      = (const float*)d_in[10];
    const float* W_sc1      = (const float*)d_in[11];
    const int*   edge_index = (const int*)d_in[12];
    float* out = (float*)d_out;

    char* p = (char*)d_ws;
    float* hid = (float*)p;                 p += (size_t)E * 8 * 4;
    u16* hc    = (u16*)p;                   p += (size_t)N * 256 * 2;
    u16* A1    = (u16*)p;                   p += (size_t)N * 192 * 2;
    u16* A2    = (u16*)p;                   p += (size_t)N * 3 * 384 * 2;
    u16* x1p   = (u16*)p;                   p += (size_t)N * 3 * 64 * 2;
    u16* Bt1m  = (u16*)p;                   p += 16384 * 2;
    u16* Bt1z  = (u16*)p;                   p += 32768 * 2;
    u16* Bt2   = (u16*)p;                   p += 24576 * 2;
    u16* W0b   = (u16*)p;                   p += 4096 * 2;
    u16* W1b   = (u16*)p;                   p += 4096 * 2;
    int* counts   = (int*)p;                p += N * 4;
    int* bar      = (int*)p;                p += 8 * 4;
    int* blockSum = (int*)p;                p += 256 * 4;
    int* offsets  = (int*)p;                p += (N + 1) * 4;
    int* cursor   = (int*)p;                p += N * 4;
    int* perm_e   = (int*)p;                p += E * 4;
    int* perm_src = (int*)p;                p += E * 4;

    // zero counts + barrier slots in one memset (contiguous)
    hipMemsetAsync(counts, 0, (N + 8) * sizeof(int), stream);

    k_front<<<PREP_B + WCONV_B + HID_B + HIST_B, 256, 0, stream>>>(
        node_feats, node_attrs, edge_emb, edge_index,
        W_lin2_0, W_sc0, W_lin2_1, W_sc1, W_lin1_0, W_lin1_1, W_mlp1,
        A1, A2, x1p, Bt1m, Bt1z, Bt2, W0b, W1b, hid, counts);
    k_csr<<<NB, 256, 0, stream>>>(counts, blockSum, bar, offsets, cursor,
                                  edge_index, perm_e, perm_src,
                                  A1, x1p, W0b, W1b, hc);
    k_gather<<<N / 2, 256, 0, stream>>>(perm_e, perm_src, offsets,
                                        edge_attrs, hid, (const u32*)hc,
                                        W_mlp2, A1, A2);
    k_gemm_fused<<<1250, 256, 0, stream>>>(A1, A2, Bt1m, Bt1z, Bt2,
                                           node_attrs, node_feats, out);
}

// Round 10
// 222.093 us; speedup vs baseline: 1.1800x; 1.1800x over previous
//
#include <hip/hip_runtime.h>
#include <hip/hip_bf16.h>
#include <math.h>

#define N 20000
#define E 160000
#define MUL 64
#define EDIM 8
#define NZ 4

#define INV_SQRT_MUL 0.125f
#define INV_E 0.35355339059327373f
#define INV_N 0.35355339059327373f
#define INV2 0.08838834764831845f
#define INV_SC 0.0625f
#define INV_SQRT3 0.5773502691896258f

typedef unsigned short u16;
typedef unsigned int u32;
typedef short bf16x8 __attribute__((ext_vector_type(8)));
typedef float f32x4 __attribute__((ext_vector_type(4)));

__device__ __forceinline__ float silu(float v) {
    return v / (1.0f + __expf(-v));
}
__device__ __forceinline__ u16 f2bf(float f) {
    union { float f; unsigned int u; } v; v.f = f;
    unsigned int r = (v.u + 0x7FFFu + ((v.u >> 16) & 1u)) >> 16;
    return (u16)r;
}
__device__ __forceinline__ float bflo(u32 p) {
    union { unsigned int u; float f; } v; v.u = p << 16; return v.f;
}
__device__ __forceinline__ float bfhi(u32 p) {
    union { unsigned int u; float f; } v; v.u = p & 0xFFFF0000u; return v.f;
}
#define MFMA(a, b, c) __builtin_amdgcn_mfma_f32_16x16x32_bf16(a, b, c, 0, 0, 0)

// Layouts:
//  A1 [N][192]:  0..127 gathered s0 (scales folded), 128..191 bf16(x0)
//  A2 [3N][384]: 0..127 gathered s1, 128..383 bf16(x1[:,d]*attr[z]*INV_SC)
//  x1p [3N][64] bf16(x1) for the h-GEMM
//  Bt1m [128][128]=W20^T; Bt1z [4][128][64]=Wsc0_z^T*INV_SC
//  Bt2 [64][384]; W0b/W1b [64][64]=lin1^T*INV_SQRT_MUL
//  head[n]: last edge with dst=n (-1 = none); nl[e] = {prev edge, src}

// ---------------------------------------------------------------------------
// Front: grid-partitioned [prep | wconv | hid | list-build]
// ---------------------------------------------------------------------------
#define PREP_B  5000
#define WCONV_B 320
#define HID_B   5000
#define LIST_B  625

__global__ __launch_bounds__(256) void k_front(
    const float* __restrict__ x, const float* __restrict__ attrs,
    const float* __restrict__ eemb, const int* __restrict__ eidx,
    const float* __restrict__ W20, const float* __restrict__ Wsc0,
    const float* __restrict__ W21, const float* __restrict__ Wsc1,
    const float* __restrict__ W0, const float* __restrict__ W1,
    const float* __restrict__ Wm1,
    u16* __restrict__ A1, u16* __restrict__ A2, u16* __restrict__ x1p,
    u16* __restrict__ Bt1m, u16* __restrict__ Bt1z, u16* __restrict__ Bt2,
    u16* __restrict__ W0b, u16* __restrict__ W1b,
    float* __restrict__ hid, int* __restrict__ head, int2* __restrict__ nl)
{
    const int b = blockIdx.x;
    const int tid = threadIdx.x;
    __shared__ float xr[4][256];

    if (b < PREP_B) {
        const int n0 = b * 4;
        #pragma unroll
        for (int t = 0; t < 4; ++t)
            xr[t][tid] = x[(size_t)(n0 + t) * 256 + tid];
        __syncthreads();
        #pragma unroll
        for (int t = 0; t < 4; ++t) {
            const int n = n0 + t;
            const float at = attrs[(size_t)n * 4 + (tid & 3)] * INV_SC;
            const int u = tid >> 2;
            #pragma unroll
            for (int d = 0; d < 3; ++d)
                A2[((size_t)n * 3 + d) * 384 + 128 + tid] = f2bf(xr[t][64 + u * 3 + d] * at);
            if (tid < 64) {
                A1[(size_t)n * 192 + 128 + tid] = f2bf(xr[t][tid]);
            } else {
                int q = tid - 64;
                int d = q >> 6, uu = q & 63;
                x1p[((size_t)n * 3 + d) * 64 + uu] = f2bf(xr[t][64 + uu * 3 + d]);
            }
        }
    } else if (b < PREP_B + WCONV_B) {
        int i = (b - PREP_B) * 256 + tid;
        if (i < 16384) {
            int w = i >> 7, k = i & 127;
            Bt1m[i] = f2bf(W20[k * 128 + w]);
        } else if (i < 49152) {
            int j = i - 16384;
            int z = j >> 13, r = j & 8191, w = r >> 6, k = r & 63;
            Bt1z[j] = f2bf(Wsc0[(k * 4 + z) * 128 + w] * INV_SC);
        } else if (i < 73728) {
            int j = i - 49152;
            int w = j / 384, k = j % 384;
            float v = (k < 128) ? W21[k * 64 + w] : Wsc1[(k - 128) * 64 + w];
            Bt2[j] = f2bf(v);
        } else if (i < 77824) {
            int j = i - 73728;
            int v = j >> 6, u = j & 63;
            W0b[j] = f2bf(W0[u * 64 + v] * INV_SQRT_MUL);
        } else {
            int j = i - 77824;
            int v = j >> 6, u = j & 63;
            W1b[j] = f2bf(W1[u * 64 + v] * INV_SQRT_MUL);
        }
    } else if (b < PREP_B + WCONV_B + HID_B) {
        int i = (b - PREP_B - WCONV_B) * 256 + tid;
        int e = i >> 3, k = i & 7;
        float s = 0.f;
        #pragma unroll
        for (int j = 0; j < 8; ++j)
            s += eemb[(size_t)e * 8 + j] * Wm1[j * 8 + k];
        hid[i] = silu(s * INV_E);
    } else {
        int e = (b - PREP_B - WCONV_B - HID_B) * 256 + tid;
        if (e < E) {
            int src = eidx[e];
            int dst = eidx[E + e];
            int old = atomicExch(&head[dst], e);
            nl[e] = make_int2(old, src);
        }
    }
}

// ---------------------------------------------------------------------------
// h-GEMM: lin1 MFMA -> hc bf16 AoS (hc[n][v][4] = g0,g1x,g1y,g1z)
// ---------------------------------------------------------------------------
__global__ __launch_bounds__(256) void k_hgemm(
    const u16* __restrict__ A1, const u16* __restrict__ x1p,
    const u16* __restrict__ W0b, const u16* __restrict__ W1b,
    u16* __restrict__ hc)
{
    const int lane = threadIdx.x & 63;
    const int g = blockIdx.x * 4 + (threadIdx.x >> 6);
    const int quad = lane >> 4, l16 = lane & 15;
    const bool isC1 = (g >= 1250);
    const int row0 = isC1 ? (g - 1250) * 16 : g * 16;
    const u16* Ap = isC1 ? (x1p + (size_t)(row0 + l16) * 64)
                         : (A1 + (size_t)(row0 + l16) * 192 + 128);
    const u16* Bp = isC1 ? W1b : W0b;

    f32x4 acc[4] = {};
    #pragma unroll
    for (int k0 = 0; k0 < 64; k0 += 32) {
        bf16x8 a = *(const bf16x8*)(Ap + k0 + quad * 8);
        #pragma unroll
        for (int ct = 0; ct < 4; ++ct) {
            bf16x8 bb = *(const bf16x8*)(Bp + (size_t)(ct * 16 + l16) * 64 + k0 + quad * 8);
            acc[ct] = MFMA(a, bb, acc[ct]);
        }
    }
    #pragma unroll
    for (int ct = 0; ct < 4; ++ct) {
        #pragma unroll
        for (int r = 0; r < 4; ++r) {
            int row = row0 + quad * 4 + r;
            int vv = ct * 16 + l16;
            if (!isC1) {
                hc[(size_t)row * 256 + vv * 4] = f2bf(acc[ct][r]);
            } else {
                int n = row / 3, d = row - 3 * (row / 3);
                hc[(size_t)n * 256 + vv * 4 + 1 + d] = f2bf(acc[ct][r]);
            }
        }
    }
}

// ---------------------------------------------------------------------------
// Gather v6: one wave per dst node, linked-list chase, software-pipelined.
// nl[e] = {next_edge, src} — wave-uniform broadcast load per hop.
// ---------------------------------------------------------------------------
__global__ __launch_bounds__(256) void k_gather(
    const int* __restrict__ head, const int2* __restrict__ nl,
    const float* __restrict__ eattr, const float* __restrict__ hid,
    const u32* __restrict__ hc2, const float* __restrict__ Wm2,
    u16* __restrict__ A1, u16* __restrict__ A2)
{
    const int lane = threadIdx.x & 63;
    const int n = blockIdx.x * 4 + (threadIdx.x >> 6);

    float wm0[8], wm1[8], wm2r[8], wm3[8];
    #pragma unroll
    for (int k = 0; k < 8; ++k) {
        wm0[k]  = Wm2[k * 256 + lane];
        wm1[k]  = Wm2[k * 256 + 64 + lane];
        wm2r[k] = Wm2[k * 256 + 128 + lane];
        wm3[k]  = Wm2[k * 256 + 192 + lane];
    }

    float acc0a = 0.f, acc0b = 0.f;
    float s1a[3] = {0.f, 0.f, 0.f}, s1b[3] = {0.f, 0.f, 0.f};

    int e = head[n];
    if (e != -1) {
        int2 v = nl[e];
        while (true) {
            const int en = v.x;
            int2 vn;
            if (en != -1) vn = nl[en];            // prefetch next hop

            const float4 ea = ((const float4*)eattr)[e];
            const float4 hA = ((const float4*)hid)[(size_t)e * 2];
            const float4 hB = ((const float4*)hid)[(size_t)e * 2 + 1];
            const uint2  hp = ((const uint2*)hc2)[(size_t)v.y * 64 + lane];

            float w1 = hA.x*wm0[0]+hA.y*wm0[1]+hA.z*wm0[2]+hA.w*wm0[3]
                     + hB.x*wm0[4]+hB.y*wm0[5]+hB.z*wm0[6]+hB.w*wm0[7];
            float w2 = hA.x*wm1[0]+hA.y*wm1[1]+hA.z*wm1[2]+hA.w*wm1[3]
                     + hB.x*wm1[4]+hB.y*wm1[5]+hB.z*wm1[6]+hB.w*wm1[7];
            float w3 = hA.x*wm2r[0]+hA.y*wm2r[1]+hA.z*wm2r[2]+hA.w*wm2r[3]
                     + hB.x*wm2r[4]+hB.y*wm2r[5]+hB.z*wm2r[6]+hB.w*wm2r[7];
            float w4 = hA.x*wm3[0]+hA.y*wm3[1]+hA.z*wm3[2]+hA.w*wm3[3]
                     + hB.x*wm3[4]+hB.y*wm3[5]+hB.z*wm3[6]+hB.w*wm3[7];
            const float g0 = bflo(hp.x), g1x = bfhi(hp.x);
            const float g1y = bflo(hp.y), g1z = bfhi(hp.y);
            acc0a += w1 * g0 * ea.x;
            acc0b += w4 * (g1x * ea.y + g1y * ea.z + g1z * ea.w);
            const float wg = w2 * g0, w3a = w3 * ea.x;
            s1a[0] += wg * ea.y;  s1a[1] += wg * ea.z;  s1a[2] += wg * ea.w;
            s1b[0] += w3a * g1x;  s1b[1] += w3a * g1y;  s1b[2] += w3a * g1z;

            if (en == -1) break;
            e = en; v = vn;
        }
    }

    const float f = INV_E * INV_N * INV2;
    u16* a1p = &A1[(size_t)n * 192];
    a1p[lane]      = f2bf(acc0a * f);
    a1p[64 + lane] = f2bf(acc0b * f * INV_SQRT3);
    #pragma unroll
    for (int d = 0; d < 3; ++d) {
        u16* a2p = &A2[((size_t)n * 3 + d) * 384];
        a2p[lane]      = f2bf(s1a[d] * f);
        a2p[64 + lane] = f2bf(s1b[d] * f);
    }
}

// ---------------------------------------------------------------------------
// Fused post-GEMM + epilogue v5 (unchanged): 16 nodes/block; t1 single-acc,
// t0 = main + 4 z-sliced accs; 13 f32x4 accumulators.
// ---------------------------------------------------------------------------
__global__ __launch_bounds__(256) void k_gemm_fused(
    const u16* __restrict__ A1, const u16* __restrict__ A2,
    const u16* __restrict__ Bt1m, const u16* __restrict__ Bt1z,
    const u16* __restrict__ Bt2,
    const float* __restrict__ attrs, const float* __restrict__ x,
    float* __restrict__ out)
{
    const int lane = threadIdx.x & 63;
    const int wave = threadIdx.x >> 6;
    const int quad = lane >> 4, l16 = lane & 15;
    const int n0 = blockIdx.x * 16;

    __shared__ float st0[16][132];
    __shared__ float st1[48][68];
    __shared__ float sat[16][4];
    if (threadIdx.x < 64)
        sat[threadIdx.x >> 2][threadIdx.x & 3] =
            attrs[(size_t)(n0 + (threadIdx.x >> 2)) * 4 + (threadIdx.x & 3)];

    const u16* a0p  = A1 + (size_t)(n0 + l16) * 192 + quad * 8;
    const u16* a1p  = A2 + (size_t)(3 * n0 + l16) * 384 + quad * 8;
    const u16* b0p  = Bt1m + (size_t)(wave * 16 + l16) * 128 + quad * 8;
    const u16* b1p  = Bt1m + (size_t)((wave + 4) * 16 + l16) * 128 + quad * 8;
    const u16* bz0p = Bt1z + (size_t)(wave * 16 + l16) * 64 + quad * 8;
    const u16* bz1p = Bt1z + (size_t)((wave + 4) * 16 + l16) * 64 + quad * 8;
    const u16* b2p  = Bt2 + (size_t)(wave * 16 + l16) * 384 + quad * 8;

    f32x4 m0 = {}, m1 = {}, m2 = {}, m3 = {}, m4 = {};
    f32x4 z0[4] = {}, z1[4] = {};

    #pragma unroll
    for (int kt = 0; kt < 12; ++kt) {
        const int ko = kt * 32;
        bf16x8 a1 = *(const bf16x8*)(a1p + ko);
        bf16x8 a2 = *(const bf16x8*)(a1p + 16 * 384 + ko);
        bf16x8 a3 = *(const bf16x8*)(a1p + 32 * 384 + ko);
        bf16x8 b2 = *(const bf16x8*)(b2p + ko);
        m2 = MFMA(a1, b2, m2);
        m3 = MFMA(a2, b2, m3);
        m4 = MFMA(a3, b2, m4);
    }
    #pragma unroll
    for (int kt = 0; kt < 4; ++kt) {
        const int ko = kt * 32;
        bf16x8 a0 = *(const bf16x8*)(a0p + ko);
        bf16x8 b0 = *(const bf16x8*)(b0p + ko);
        bf16x8 b1 = *(const bf16x8*)(b1p + ko);
        m0 = MFMA(a0, b0, m0);
        m1 = MFMA(a0, b1, m1);
    }
    #pragma unroll
    for (int kt = 0; kt < 2; ++kt) {
        const int ko = kt * 32;
        bf16x8 a0 = *(const bf16x8*)(a0p + 128 + ko);
        #pragma unroll
        for (int z = 0; z < 4; ++z) {
            bf16x8 c0 = *(const bf16x8*)(bz0p + z * 8192 + ko);
            bf16x8 c1 = *(const bf16x8*)(bz1p + z * 8192 + ko);
            z0[z] = MFMA(a0, c0, z0[z]);
            z1[z] = MFMA(a0, c1, z1[z]);
        }
    }
    __syncthreads();

    #pragma unroll
    for (int r = 0; r < 4; ++r) {
        const int r0 = quad * 4 + r;
        const float ta = sat[r0][0], tb = sat[r0][1],
                    tc = sat[r0][2], td = sat[r0][3];
        st0[r0][wave * 16 + l16] =
            m0[r] + ta * z0[0][r] + tb * z0[1][r] + tc * z0[2][r] + td * z0[3][r];
        st0[r0][(wave + 4) * 16 + l16] =
            m1[r] + ta * z1[0][r] + tb * z1[1][r] + tc * z1[2][r] + td * z1[3][r];
        st1[r0][wave * 16 + l16]      = m2[r];
        st1[16 + r0][wave * 16 + l16] = m3[r];
        st1[32 + r0][wave * 16 + l16] = m4[r];
    }
    __syncthreads();

    const int c = threadIdx.x;
    #pragma unroll
    for (int t = 0; t < 16; ++t) {
        const float xv = x[(size_t)(n0 + t) * 256 + c];
        float o;
        if (c < 64) {
            o = xv + silu(st0[t][c]);
        } else {
            int r = c - 64;
            int w = (r * 21846) >> 16;      // r/3
            int d = r - w * 3;
            o = xv + silu(st0[t][64 + w]) * st1[t * 3 + d][w];
        }
        out[(size_t)(n0 + t) * 256 + c] = o;
    }
}

extern "C" void kernel_launch(void* const* d_in, const int* in_sizes, int n_in,
                              void* d_out, int out_size, void* d_ws, size_t ws_size,
                              hipStream_t stream) {
    const float* node_feats = (const float*)d_in[0];
    const float* node_attrs = (const float*)d_in[1];
    const float* edge_attrs = (const float*)d_in[2];
    const float* edge_emb   = (const float*)d_in[3];
    const float* W_lin1_0   = (const float*)d_in[4];
    const float* W_lin1_1   = (const float*)d_in[5];
    const float* W_mlp1     = (const float*)d_in[6];
    const float* W_mlp2     = (const float*)d_in[7];
    const float* W_lin2_0   = (const float*)d_in[8];
    const float* W_lin2_1   = (const float*)d_in[9];
    const float* W_sc0      = (const float*)d_in[10];
    const float* W_sc1      = (const float*)d_in[11];
    const int*   edge_index = (const int*)d_in[12];
    float* out = (float*)d_out;

    char* p = (char*)d_ws;
    float* hid = (float*)p;                 p += (size_t)E * 8 * 4;
    u16* hc    = (u16*)p;                   p += (size_t)N * 256 * 2;
    u16* A1    = (u16*)p;                   p += (size_t)N * 192 * 2;
    u16* A2    = (u16*)p;                   p += (size_t)N * 3 * 384 * 2;
    u16* x1p   = (u16*)p;                   p += (size_t)N * 3 * 64 * 2;
    u16* Bt1m  = (u16*)p;                   p += 16384 * 2;
    u16* Bt1z  = (u16*)p;                   p += 32768 * 2;
    u16* Bt2   = (u16*)p;                   p += 24576 * 2;
    u16* W0b   = (u16*)p;                   p += 4096 * 2;
    u16* W1b   = (u16*)p;                   p += 4096 * 2;
    int* head  = (int*)p;                   p += N * 4;
    int2* nl   = (int2*)p;                  p += (size_t)E * 8;

    // head = -1 everywhere (0xFF bytes)
    hipMemsetAsync(head, 0xFF, N * sizeof(int), stream);

    k_front<<<PREP_B + WCONV_B + HID_B + LIST_B, 256, 0, stream>>>(
        node_feats, node_attrs, edge_emb, edge_index,
        W_lin2_0, W_sc0, W_lin2_1, W_sc1, W_lin1_0, W_lin1_1, W_mlp1,
        A1, A2, x1p, Bt1m, Bt1z, Bt2, W0b, W1b, hid, head, nl);
    k_hgemm<<<1250, 256, 0, stream>>>(A1, x1p, W0b, W1b, hc);
    k_gather<<<N / 4, 256, 0, stream>>>(head, nl, edge_attrs, hid,
                                        (const u32*)hc, W_mlp2, A1, A2);
    k_gemm_fused<<<1250, 256, 0, stream>>>(A1, A2, Bt1m, Bt1z, Bt2,
                                           node_attrs, node_feats, out);
}

// Round 11
// 213.285 us; speedup vs baseline: 1.2287x; 1.0413x over previous
//
#include <hip/hip_runtime.h>
#include <hip/hip_bf16.h>
#include <math.h>

#define N 20000
#define E 160000
#define MUL 64
#define EDIM 8
#define NZ 4

#define INV_SQRT_MUL 0.125f
#define INV_E 0.35355339059327373f
#define INV_N 0.35355339059327373f
#define INV2 0.08838834764831845f
#define INV_SC 0.0625f
#define INV_SQRT3 0.5773502691896258f

typedef unsigned short u16;
typedef unsigned int u32;
typedef short bf16x8 __attribute__((ext_vector_type(8)));
typedef float f32x4 __attribute__((ext_vector_type(4)));

__device__ __forceinline__ float silu(float v) {
    return v / (1.0f + __expf(-v));
}
__device__ __forceinline__ u16 f2bf(float f) {
    union { float f; unsigned int u; } v; v.f = f;
    unsigned int r = (v.u + 0x7FFFu + ((v.u >> 16) & 1u)) >> 16;
    return (u16)r;
}
__device__ __forceinline__ float bflo(u32 p) {
    union { unsigned int u; float f; } v; v.u = p << 16; return v.f;
}
__device__ __forceinline__ float bfhi(u32 p) {
    union { unsigned int u; float f; } v; v.u = p & 0xFFFF0000u; return v.f;
}
#define MFMA(a, b, c) __builtin_amdgcn_mfma_f32_16x16x32_bf16(a, b, c, 0, 0, 0)

// Layouts:
//  A1  [N][192]:  0..127 gathered s0 (scales folded), 128..191 bf16(x0)
//  A2g [3N][128]: gathered s1 only (xz tail now computed on the fly in fused)
//  x1p [3N][64] bf16(x1)
//  Bt1m [128][128]=W20^T; Bt1z [4][128][64]=Wsc0_z^T*INV_SC
//  Bt2 [64][384] (k<128: W21^T; k>=128: Wsc1 flat u*4+z)
//  W0b/W1b [64][64]=lin1^T*INV_SQRT_MUL
//  head[n]: last edge with dst=n (-1 none); nl[e] = {prev edge, src}

// ---------------------------------------------------------------------------
// Front: grid-partitioned [prep | wconv | hid | list-build]
// ---------------------------------------------------------------------------
#define PREP_B  5000
#define WCONV_B 320
#define HID_B   5000
#define LIST_B  625

__global__ __launch_bounds__(256) void k_front(
    const float* __restrict__ x,
    const float* __restrict__ eemb, const int* __restrict__ eidx,
    const float* __restrict__ W20, const float* __restrict__ Wsc0,
    const float* __restrict__ W21, const float* __restrict__ Wsc1,
    const float* __restrict__ W0, const float* __restrict__ W1,
    const float* __restrict__ Wm1,
    u16* __restrict__ A1, u16* __restrict__ x1p,
    u16* __restrict__ Bt1m, u16* __restrict__ Bt1z, u16* __restrict__ Bt2,
    u16* __restrict__ W0b, u16* __restrict__ W1b,
    float* __restrict__ hid, int* __restrict__ head, int2* __restrict__ nl)
{
    const int b = blockIdx.x;
    const int tid = threadIdx.x;
    __shared__ float xr[4][256];

    if (b < PREP_B) {
        const int n0 = b * 4;
        #pragma unroll
        for (int t = 0; t < 4; ++t)
            xr[t][tid] = x[(size_t)(n0 + t) * 256 + tid];
        __syncthreads();
        #pragma unroll
        for (int t = 0; t < 4; ++t) {
            const int n = n0 + t;
            if (tid < 64) {
                A1[(size_t)n * 192 + 128 + tid] = f2bf(xr[t][tid]);
            } else {
                int q = tid - 64;
                int d = q >> 6, uu = q & 63;
                x1p[((size_t)n * 3 + d) * 64 + uu] = f2bf(xr[t][64 + uu * 3 + d]);
            }
        }
    } else if (b < PREP_B + WCONV_B) {
        int i = (b - PREP_B) * 256 + tid;
        if (i < 16384) {
            int w = i >> 7, k = i & 127;
            Bt1m[i] = f2bf(W20[k * 128 + w]);
        } else if (i < 49152) {
            int j = i - 16384;
            int z = j >> 13, r = j & 8191, w = r >> 6, k = r & 63;
            Bt1z[j] = f2bf(Wsc0[(k * 4 + z) * 128 + w] * INV_SC);
        } else if (i < 73728) {
            int j = i - 49152;
            int w = j / 384, k = j % 384;
            float v = (k < 128) ? W21[k * 64 + w] : Wsc1[(k - 128) * 64 + w];
            Bt2[j] = f2bf(v);
        } else if (i < 77824) {
            int j = i - 73728;
            int v = j >> 6, u = j & 63;
            W0b[j] = f2bf(W0[u * 64 + v] * INV_SQRT_MUL);
        } else {
            int j = i - 77824;
            int v = j >> 6, u = j & 63;
            W1b[j] = f2bf(W1[u * 64 + v] * INV_SQRT_MUL);
        }
    } else if (b < PREP_B + WCONV_B + HID_B) {
        int i = (b - PREP_B - WCONV_B) * 256 + tid;
        int e = i >> 3, k = i & 7;
        float s = 0.f;
        #pragma unroll
        for (int j = 0; j < 8; ++j)
            s += eemb[(size_t)e * 8 + j] * Wm1[j * 8 + k];
        hid[i] = silu(s * INV_E);
    } else {
        int e = (b - PREP_B - WCONV_B - HID_B) * 256 + tid;
        if (e < E) {
            int src = eidx[e];
            int dst = eidx[E + e];
            int old = atomicExch(&head[dst], e);
            nl[e] = make_int2(old, src);
        }
    }
}

// ---------------------------------------------------------------------------
// h-GEMM: lin1 MFMA -> hc bf16 AoS (hc[n][v][4] = g0,g1x,g1y,g1z)
// ---------------------------------------------------------------------------
__global__ __launch_bounds__(256) void k_hgemm(
    const u16* __restrict__ A1, const u16* __restrict__ x1p,
    const u16* __restrict__ W0b, const u16* __restrict__ W1b,
    u16* __restrict__ hc)
{
    const int lane = threadIdx.x & 63;
    const int g = blockIdx.x * 4 + (threadIdx.x >> 6);
    const int quad = lane >> 4, l16 = lane & 15;
    const bool isC1 = (g >= 1250);
    const int row0 = isC1 ? (g - 1250) * 16 : g * 16;
    const u16* Ap = isC1 ? (x1p + (size_t)(row0 + l16) * 64)
                         : (A1 + (size_t)(row0 + l16) * 192 + 128);
    const u16* Bp = isC1 ? W1b : W0b;

    f32x4 acc[4] = {};
    #pragma unroll
    for (int k0 = 0; k0 < 64; k0 += 32) {
        bf16x8 a = *(const bf16x8*)(Ap + k0 + quad * 8);
        #pragma unroll
        for (int ct = 0; ct < 4; ++ct) {
            bf16x8 bb = *(const bf16x8*)(Bp + (size_t)(ct * 16 + l16) * 64 + k0 + quad * 8);
            acc[ct] = MFMA(a, bb, acc[ct]);
        }
    }
    #pragma unroll
    for (int ct = 0; ct < 4; ++ct) {
        #pragma unroll
        for (int r = 0; r < 4; ++r) {
            int row = row0 + quad * 4 + r;
            int vv = ct * 16 + l16;
            if (!isC1) {
                hc[(size_t)row * 256 + vv * 4] = f2bf(acc[ct][r]);
            } else {
                int n = row / 3, d = row - 3 * (row / 3);
                hc[(size_t)n * 256 + vv * 4 + 1 + d] = f2bf(acc[ct][r]);
            }
        }
    }
}

// ---------------------------------------------------------------------------
// Gather v7: one wave per dst node; linked-list chase with depth-2 pipeline
// (next payload + next-next nl issued every iteration).
// ---------------------------------------------------------------------------
__global__ __launch_bounds__(256) void k_gather(
    const int* __restrict__ head, const int2* __restrict__ nl,
    const float* __restrict__ eattr, const float* __restrict__ hid,
    const u32* __restrict__ hc2, const float* __restrict__ Wm2,
    u16* __restrict__ A1, u16* __restrict__ A2g)
{
    const int lane = threadIdx.x & 63;
    const int n = blockIdx.x * 4 + (threadIdx.x >> 6);

    float wm0[8], wm1[8], wm2r[8], wm3[8];
    #pragma unroll
    for (int k = 0; k < 8; ++k) {
        wm0[k]  = Wm2[k * 256 + lane];
        wm1[k]  = Wm2[k * 256 + 64 + lane];
        wm2r[k] = Wm2[k * 256 + 128 + lane];
        wm3[k]  = Wm2[k * 256 + 192 + lane];
    }

    float acc0a = 0.f, acc0b = 0.f;
    float s1a[3] = {0.f, 0.f, 0.f}, s1b[3] = {0.f, 0.f, 0.f};

    int e0 = head[n];
    if (e0 != -1) {
        int2 v0 = nl[e0];
        float4 ea = ((const float4*)eattr)[e0];
        float4 hA = ((const float4*)hid)[(size_t)e0 * 2];
        float4 hB = ((const float4*)hid)[(size_t)e0 * 2 + 1];
        uint2  hp = ((const uint2*)hc2)[(size_t)v0.y * 64 + lane];
        int e1 = v0.x;
        int2 v1 = make_int2(-1, 0);
        if (e1 != -1) v1 = nl[e1];

        while (true) {
            int e2 = -1;
            int2 v2 = make_int2(-1, 0);
            float4 eaN, hAN, hBN; uint2 hpN;
            if (e1 != -1) {
                e2 = v1.x;
                if (e2 != -1) v2 = nl[e2];
                eaN = ((const float4*)eattr)[e1];
                hAN = ((const float4*)hid)[(size_t)e1 * 2];
                hBN = ((const float4*)hid)[(size_t)e1 * 2 + 1];
                hpN = ((const uint2*)hc2)[(size_t)v1.y * 64 + lane];
            }

            float w1 = hA.x*wm0[0]+hA.y*wm0[1]+hA.z*wm0[2]+hA.w*wm0[3]
                     + hB.x*wm0[4]+hB.y*wm0[5]+hB.z*wm0[6]+hB.w*wm0[7];
            float w2 = hA.x*wm1[0]+hA.y*wm1[1]+hA.z*wm1[2]+hA.w*wm1[3]
                     + hB.x*wm1[4]+hB.y*wm1[5]+hB.z*wm1[6]+hB.w*wm1[7];
            float w3 = hA.x*wm2r[0]+hA.y*wm2r[1]+hA.z*wm2r[2]+hA.w*wm2r[3]
                     + hB.x*wm2r[4]+hB.y*wm2r[5]+hB.z*wm2r[6]+hB.w*wm2r[7];
            float w4 = hA.x*wm3[0]+hA.y*wm3[1]+hA.z*wm3[2]+hA.w*wm3[3]
                     + hB.x*wm3[4]+hB.y*wm3[5]+hB.z*wm3[6]+hB.w*wm3[7];
            const float g0 = bflo(hp.x), g1x = bfhi(hp.x);
            const float g1y = bflo(hp.y), g1z = bfhi(hp.y);
            acc0a += w1 * g0 * ea.x;
            acc0b += w4 * (g1x * ea.y + g1y * ea.z + g1z * ea.w);
            const float wg = w2 * g0, w3a = w3 * ea.x;
            s1a[0] += wg * ea.y;  s1a[1] += wg * ea.z;  s1a[2] += wg * ea.w;
            s1b[0] += w3a * g1x;  s1b[1] += w3a * g1y;  s1b[2] += w3a * g1z;

            if (e1 == -1) break;
            ea = eaN; hA = hAN; hB = hBN; hp = hpN;
            e1 = e2; v1 = v2;
        }
    }

    const float f = INV_E * INV_N * INV2;
    u16* a1p = &A1[(size_t)n * 192];
    a1p[lane]      = f2bf(acc0a * f);
    a1p[64 + lane] = f2bf(acc0b * f * INV_SQRT3);
    #pragma unroll
    for (int d = 0; d < 3; ++d) {
        u16* a2p = &A2g[((size_t)n * 3 + d) * 128];
        a2p[lane]      = f2bf(s1a[d] * f);
        a2p[64 + lane] = f2bf(s1b[d] * f);
    }
}

// ---------------------------------------------------------------------------
// Fused post-GEMM + epilogue v6: 16 nodes/block; t1-sc A-fragments computed
// on the fly from x1p + attrs (no materialized xz tail). 13 f32x4 accs.
// ---------------------------------------------------------------------------
__global__ __launch_bounds__(256) void k_gemm_fused(
    const u16* __restrict__ A1, const u16* __restrict__ A2g,
    const u16* __restrict__ x1p,
    const u16* __restrict__ Bt1m, const u16* __restrict__ Bt1z,
    const u16* __restrict__ Bt2,
    const float* __restrict__ attrs, const float* __restrict__ x,
    float* __restrict__ out)
{
    const int lane = threadIdx.x & 63;
    const int wave = threadIdx.x >> 6;
    const int quad = lane >> 4, l16 = lane & 15;
    const int n0 = blockIdx.x * 16;

    __shared__ float st0[16][132];
    __shared__ float st1[48][68];
    __shared__ float sat[16][4];
    if (threadIdx.x < 64)
        sat[threadIdx.x >> 2][threadIdx.x & 3] =
            attrs[(size_t)(n0 + (threadIdx.x >> 2)) * 4 + (threadIdx.x & 3)];
    __syncthreads();

    // per-lane attr*INV_SC for the 3 t1 row-tiles (row = 3*n0 + rt*16 + l16)
    float atv[3][4];
    #pragma unroll
    for (int rt = 0; rt < 3; ++rt) {
        const int ro = rt * 16 + l16;            // 0..47
        const int nn = (ro * 21846) >> 16;       // ro/3
        #pragma unroll
        for (int z = 0; z < 4; ++z) atv[rt][z] = sat[nn][z] * INV_SC;
    }

    const u16* a0p  = A1  + (size_t)(n0 + l16) * 192 + quad * 8;
    const u16* a1p  = A2g + (size_t)(3 * n0 + l16) * 128 + quad * 8;
    const u16* b0p  = Bt1m + (size_t)(wave * 16 + l16) * 128 + quad * 8;
    const u16* b1p  = Bt1m + (size_t)((wave + 4) * 16 + l16) * 128 + quad * 8;
    const u16* bz0p = Bt1z + (size_t)(wave * 16 + l16) * 64 + quad * 8;
    const u16* bz1p = Bt1z + (size_t)((wave + 4) * 16 + l16) * 64 + quad * 8;
    const u16* b2p  = Bt2 + (size_t)(wave * 16 + l16) * 384 + quad * 8;
    const u16* xq0  = x1p + (size_t)(3 * n0 + l16) * 64 + quad * 2;
    const u16* xq1  = x1p + (size_t)(3 * n0 + 16 + l16) * 64 + quad * 2;
    const u16* xq2  = x1p + (size_t)(3 * n0 + 32 + l16) * 64 + quad * 2;

    f32x4 m0 = {}, m1 = {};
    f32x4 mt[3] = {};
    f32x4 z0[4] = {}, z1[4] = {};

    // t1 main: gathered 128 cols of A2g
    #pragma unroll
    for (int kt = 0; kt < 4; ++kt) {
        const int ko = kt * 32;
        bf16x8 a1 = *(const bf16x8*)(a1p + ko);
        bf16x8 a2 = *(const bf16x8*)(a1p + 16 * 128 + ko);
        bf16x8 a3 = *(const bf16x8*)(a1p + 32 * 128 + ko);
        bf16x8 b2 = *(const bf16x8*)(b2p + ko);
        mt[0] = MFMA(a1, b2, mt[0]);
        mt[1] = MFMA(a2, b2, mt[1]);
        mt[2] = MFMA(a3, b2, mt[2]);
    }
    // t1 sc: A-fragment = bf16(x1[u]*attr[z]*INV_SC) computed on the fly
    #pragma unroll
    for (int kt = 0; kt < 8; ++kt) {
        bf16x8 b2 = *(const bf16x8*)(b2p + 128 + kt * 32);
        const u32 xpa = *(const u32*)(xq0 + kt * 8);
        const u32 xpb = *(const u32*)(xq1 + kt * 8);
        const u32 xpc = *(const u32*)(xq2 + kt * 8);
        #pragma unroll
        for (int rt = 0; rt < 3; ++rt) {
            const u32 xp = (rt == 0) ? xpa : (rt == 1) ? xpb : xpc;
            const float xa = bflo(xp), xb = bfhi(xp);
            bf16x8 af;
            #pragma unroll
            for (int j = 0; j < 4; ++j) af[j] = (short)f2bf(xa * atv[rt][j]);
            #pragma unroll
            for (int j = 0; j < 4; ++j) af[4 + j] = (short)f2bf(xb * atv[rt][j]);
            mt[rt] = MFMA(af, b2, mt[rt]);
        }
    }
    // t0 main
    #pragma unroll
    for (int kt = 0; kt < 4; ++kt) {
        const int ko = kt * 32;
        bf16x8 a0 = *(const bf16x8*)(a0p + ko);
        bf16x8 b0 = *(const bf16x8*)(b0p + ko);
        bf16x8 b1 = *(const bf16x8*)(b1p + ko);
        m0 = MFMA(a0, b0, m0);
        m1 = MFMA(a0, b1, m1);
    }
    // t0 sc: x0 @ Wsc0_z (z-sliced B, combined with attr in epilogue)
    #pragma unroll
    for (int kt = 0; kt < 2; ++kt) {
        const int ko = kt * 32;
        bf16x8 a0 = *(const bf16x8*)(a0p + 128 + ko);
        #pragma unroll
        for (int z = 0; z < 4; ++z) {
            bf16x8 c0 = *(const bf16x8*)(bz0p + z * 8192 + ko);
            bf16x8 c1 = *(const bf16x8*)(bz1p + z * 8192 + ko);
            z0[z] = MFMA(a0, c0, z0[z]);
            z1[z] = MFMA(a0, c1, z1[z]);
        }
    }
    __syncthreads();

    #pragma unroll
    for (int r = 0; r < 4; ++r) {
        const int r0 = quad * 4 + r;
        const float ta = sat[r0][0], tb = sat[r0][1],
                    tc = sat[r0][2], td = sat[r0][3];
        st0[r0][wave * 16 + l16] =
            m0[r] + ta * z0[0][r] + tb * z0[1][r] + tc * z0[2][r] + td * z0[3][r];
        st0[r0][(wave + 4) * 16 + l16] =
            m1[r] + ta * z1[0][r] + tb * z1[1][r] + tc * z1[2][r] + td * z1[3][r];
        st1[r0][wave * 16 + l16]      = mt[0][r];
        st1[16 + r0][wave * 16 + l16] = mt[1][r];
        st1[32 + r0][wave * 16 + l16] = mt[2][r];
    }
    __syncthreads();

    const int c = threadIdx.x;
    #pragma unroll
    for (int t = 0; t < 16; ++t) {
        const float xv = x[(size_t)(n0 + t) * 256 + c];
        float o;
        if (c < 64) {
            o = xv + silu(st0[t][c]);
        } else {
            int r = c - 64;
            int w = (r * 21846) >> 16;      // r/3
            int d = r - w * 3;
            o = xv + silu(st0[t][64 + w]) * st1[t * 3 + d][w];
        }
        out[(size_t)(n0 + t) * 256 + c] = o;
    }
}

extern "C" void kernel_launch(void* const* d_in, const int* in_sizes, int n_in,
                              void* d_out, int out_size, void* d_ws, size_t ws_size,
                              hipStream_t stream) {
    const float* node_feats = (const float*)d_in[0];
    const float* node_attrs = (const float*)d_in[1];
    const float* edge_attrs = (const float*)d_in[2];
    const float* edge_emb   = (const float*)d_in[3];
    const float* W_lin1_0   = (const float*)d_in[4];
    const float* W_lin1_1   = (const float*)d_in[5];
    const float* W_mlp1     = (const float*)d_in[6];
    const float* W_mlp2     = (const float*)d_in[7];
    const float* W_lin2_0   = (const float*)d_in[8];
    const float* W_lin2_1   = (const float*)d_in[9];
    const float* W_sc0      = (const float*)d_in[10];
    const float* W_sc1      = (const float*)d_in[11];
    const int*   edge_index = (const int*)d_in[12];
    float* out = (float*)d_out;

    char* p = (char*)d_ws;
    float* hid = (float*)p;                 p += (size_t)E * 8 * 4;
    u16* hc    = (u16*)p;                   p += (size_t)N * 256 * 2;
    u16* A1    = (u16*)p;                   p += (size_t)N * 192 * 2;
    u16* A2g   = (u16*)p;                   p += (size_t)N * 3 * 128 * 2;
    u16* x1p   = (u16*)p;                   p += (size_t)N * 3 * 64 * 2;
    u16* Bt1m  = (u16*)p;                   p += 16384 * 2;
    u16* Bt1z  = (u16*)p;                   p += 32768 * 2;
    u16* Bt2   = (u16*)p;                   p += 24576 * 2;
    u16* W0b   = (u16*)p;                   p += 4096 * 2;
    u16* W1b   = (u16*)p;                   p += 4096 * 2;
    int* head  = (int*)p;                   p += N * 4;
    int2* nl   = (int2*)p;                  p += (size_t)E * 8;

    hipMemsetAsync(head, 0xFF, N * sizeof(int), stream);

    k_front<<<PREP_B + WCONV_B + HID_B + LIST_B, 256, 0, stream>>>(
        node_feats, edge_emb, edge_index,
        W_lin2_0, W_sc0, W_lin2_1, W_sc1, W_lin1_0, W_lin1_1, W_mlp1,
        A1, x1p, Bt1m, Bt1z, Bt2, W0b, W1b, hid, head, nl);
    k_hgemm<<<1250, 256, 0, stream>>>(A1, x1p, W0b, W1b, hc);
    k_gather<<<N / 4, 256, 0, stream>>>(head, nl, edge_attrs, hid,
                                        (const u32*)hc, W_mlp2, A1, A2g);
    k_gemm_fused<<<1250, 256, 0, stream>>>(A1, A2g, x1p, Bt1m, Bt1z, Bt2,
                                           node_attrs, node_feats, out);
}